// Round 13
// baseline (885.783 us; speedup 1.0000x reference)
//
#include <hip/hip_runtime.h>
#include <cstddef>

// ---------------- problem constants ----------------
#define Bq    4
#define Hh    12
#define Dd    64
#define NNtok 1280
#define DIMc  768
#define KAUG  800      // 768 + 32 augmented-K for fused LoRA
#define NBH   48       // Bq*Hh

typedef __attribute__((ext_vector_type(8))) short bf16x8;
typedef __attribute__((ext_vector_type(4))) float f32x4;

// workspace offsets (floats)
static const size_t OVb   = 0;                   // (unused since r11: v goes GEMM->vth directly)
static const size_t OXO   = 3932160;             // xo fp32 (B,1280,768)
static const size_t OQL   = 7864320;             // qkv low (5120,24)
static const size_t OIDK  = 7987200;             // 1+tanh(ID_K) (1024,12)
static const size_t OIDV  = 7999488;             // ID_V (1024,768)
static const size_t OLK   = 8785920;             // id_lowk (1024,8)
static const size_t OLV   = 8794112;             // id_lowv (1024,8)
static const size_t OQH   = 8986624;             // qh bf16 (B,H,1280,64)
static const size_t OKFH  = 10952704;            // kfh bf16 (B,H,2560,64) [mem_k|k]
static const size_t OVTH  = 14884864;            // vth bf16 (B,H,64,2560)
static const size_t OKMH  = 18817024;            // kmh bf16 (B,H,256,64)
static const size_t OVMTH = 19210240;            // vmth bf16 (B,H,64,256)
static const size_t OAa   = 19603456;            // A_aug bf16 (5120,800)
static const size_t OWa   = 21651456;            // W_aug qkv bf16 (2304,800)
static const size_t OWa2  = 22573056;            // W_aug proj bf16 (768,800)

// d_out offsets (floats)
static const size_t KMID_OFF = 3932160;
static const size_t VMID_OFF = 4718592;

__device__ __forceinline__ unsigned int pk_bf16(float a, float b) {  // RNE pack
  unsigned int ua = __float_as_uint(a), ub = __float_as_uint(b);
  ua += 0x7fffu + ((ua >> 16) & 1u);
  ub += 0x7fffu + ((ub >> 16) & 1u);
  return (ua >> 16) | (ub & 0xffff0000u);
}
__device__ __forceinline__ unsigned short bf16_1(float a) {
  unsigned int ua = __float_as_uint(a);
  ua += 0x7fffu + ((ua >> 16) & 1u);
  return (unsigned short)(ua >> 16);
}
__device__ __forceinline__ float bf2f(unsigned int h) {
  return __uint_as_float(h << 16);
}

// ---------------- prep: cast_k | transpose(mem_v) | cast_w_qkv | cast_w_proj
//                  | fused LoRA down-dots (qlow, id lowk/lowv) ----------------
__global__ __launch_bounds__(256) void prep(
    const float* __restrict__ mem_k, const float* __restrict__ mem_v,
    const float* __restrict__ W_qkv, const float* __restrict__ qkvB,
    const float* __restrict__ W_proj, const float* __restrict__ projB,
    unsigned short* __restrict__ kfh, unsigned short* __restrict__ vth,
    unsigned short* __restrict__ Wa, unsigned short* __restrict__ Wa2,
    const float* __restrict__ x, const float* __restrict__ qkvA,
    float* __restrict__ qlow,
    const float* __restrict__ id_tot, const float* __restrict__ idkA,
    const float* __restrict__ idvA, float* __restrict__ lowk,
    float* __restrict__ lowv)
{
  __shared__ float tl[64][65];
  const int blk = blockIdx.x, t = threadIdx.x;
  if (blk < 1920) {                       // cast mem_k -> kfh rows 0..1279
    size_t idx = ((size_t)blk * 256 + t) * 8;
    int bh = (int)(idx / 81920);
    int r  = (int)(idx % 81920);
    const float* s = mem_k + (size_t)bh * 81920 + r;
    float4 a = *(const float4*)s;
    float4 b = *(const float4*)(s + 4);
    unsigned int* dp = (unsigned int*)(kfh + (size_t)bh * 163840 + r);
    dp[0] = pk_bf16(a.x, a.y); dp[1] = pk_bf16(a.z, a.w);
    dp[2] = pk_bf16(b.x, b.y); dp[3] = pk_bf16(b.z, b.w);
  } else if (blk < 2880) {                // transpose mem_v -> vth cols 0..1279
    int b2 = blk - 1920;
    int bh = b2 / 20, t0 = (b2 % 20) * 64;
    const float* sb = mem_v + (size_t)bh * 81920 + (size_t)t0 * 64;
#pragma unroll
    for (int p = 0; p < 4; ++p) {
      int flat = p * 256 + t;
      int r = flat >> 4, c4 = (flat & 15) << 2;
      float4 v = *(const float4*)(sb + r * 64 + c4);
      tl[r][c4 + 0] = v.x; tl[r][c4 + 1] = v.y;
      tl[r][c4 + 2] = v.z; tl[r][c4 + 3] = v.w;
    }
    __syncthreads();
    unsigned short* db = vth + (size_t)bh * 163840 + t0;
#pragma unroll
    for (int p = 0; p < 8; ++p) {
      int flat = p * 256 + t;
      int d = flat >> 5, u = flat & 31;
      *(unsigned int*)(db + (size_t)d * 2560 + 2 * u) = pk_bf16(tl[2 * u][d], tl[2 * u + 1][d]);
    }
  } else if (blk < 6480) {                // W_aug qkv
    int idx = (blk - 2880) * 256 + t;     // 2304*400 uint pairs
    int row = idx / 400, c = (idx % 400) * 2;
    float a, b;
    if (c < 768) {
      a = W_qkv[(size_t)row * 768 + c]; b = W_qkv[(size_t)row * 768 + c + 1];
    } else {
      int g = row / 768, jj = row % 768;
      int e0 = c - 768, e1 = e0 + 1;
      a = (e0 < 24 && (e0 >> 3) == g) ? qkvB[(size_t)g * 6144 + jj * 8 + (e0 & 7)] * 0.125f : 0.f;
      b = (e1 < 24 && (e1 >> 3) == g) ? qkvB[(size_t)g * 6144 + jj * 8 + (e1 & 7)] * 0.125f : 0.f;
    }
    *(unsigned int*)(Wa + (size_t)row * KAUG + c) = pk_bf16(a, b);
  } else if (blk < 7680) {                // W_aug proj
    int idx = (blk - 6480) * 256 + t;     // 768*400
    int row = idx / 400, c = (idx % 400) * 2;
    float a, b;
    if (c < 768) {
      a = W_proj[(size_t)row * 768 + c]; b = W_proj[(size_t)row * 768 + c + 1];
    } else {
      int e0 = c - 768, e1 = e0 + 1;
      a = projB[(size_t)(e0 >> 3) * 6144 + row * 8 + (e0 & 7)];
      b = projB[(size_t)(e1 >> 3) * 6144 + row * 8 + (e1 & 7)];
    }
    *(unsigned int*)(Wa2 + (size_t)row * KAUG + c) = pk_bf16(a, b);
  } else {                                // fused LoRA down-dots
    const int wv = t >> 6, ln = t & 63;
    int b2 = blk - 7680;
    if (b2 < 1280) {                      // qlow: 5120 rows x 24 outputs
      size_t row = (size_t)b2 * 4 + wv;
      const float* s = x + row * DIMc;
      float xr[12];
#pragma unroll
      for (int i = 0; i < 12; ++i) xr[i] = s[ln + i * 64];
      float p[24];
#pragma unroll
      for (int o = 0; o < 24; ++o) {
        const float* m = qkvA + (size_t)o * DIMc;
        float acc = 0.f;
#pragma unroll
        for (int i = 0; i < 12; ++i) acc += xr[i] * m[ln + i * 64];
        p[o] = acc;
      }
#pragma unroll
      for (int off = 32; off; off >>= 1)
#pragma unroll
        for (int o = 0; o < 24; ++o) p[o] += __shfl_xor(p[o], off, 64);
      if (ln == 0) {
#pragma unroll
        for (int o = 0; o < 24; ++o) qlow[row * 24 + o] = p[o];
      }
    } else {                              // id lows: 1024 rows x (8+8)
      size_t row = (size_t)(b2 - 1280) * 4 + wv;
      const float* s = id_tot + row * DIMc;
      float xr[12];
#pragma unroll
      for (int i = 0; i < 12; ++i) xr[i] = s[ln + i * 64];
      float p[16];
#pragma unroll
      for (int o = 0; o < 8; ++o) {
        const float* m1 = idkA + (size_t)o * DIMc;
        const float* m2 = idvA + (size_t)o * DIMc;
        float a1 = 0.f, a2 = 0.f;
#pragma unroll
        for (int i = 0; i < 12; ++i) {
          a1 += xr[i] * m1[ln + i * 64];
          a2 += xr[i] * m2[ln + i * 64];
        }
        p[o] = a1; p[8 + o] = a2;
      }
#pragma unroll
      for (int off = 32; off; off >>= 1)
#pragma unroll
        for (int o = 0; o < 16; ++o) p[o] += __shfl_xor(p[o], off, 64);
      if (ln == 0) {
#pragma unroll
        for (int o = 0; o < 8; ++o) { lowk[row * 8 + o] = p[o]; lowv[row * 8 + o] = p[8 + o]; }
      }
    }
  }
}

// ---------------- merged: idv GEMM (blocks 0..191) | idk tanh (192..447)
//                  | cast_pack A_aug qkv (448..2447) ----------------
__global__ __launch_bounds__(256) void idv_idk_cast(
    const float* __restrict__ id_tot,
    const float* __restrict__ W_idv, const float* __restrict__ b_idv,
    const float* __restrict__ lowv, const float* __restrict__ idv_B,
    float* __restrict__ IDV,
    const float* __restrict__ W_idk, const float* __restrict__ b_idk,
    const float* __restrict__ lowk, const float* __restrict__ idk_B,
    float* __restrict__ IDK,
    const float* __restrict__ x, const float* __restrict__ qlow,
    unsigned short* __restrict__ Aa)
{
  __shared__ alignas(16) float As[16][68];
  __shared__ alignas(16) float Bs[16][68];
  const int blk = blockIdx.x, t = threadIdx.x;
  if (blk < 192) {   // ID_V fp32 GEMM, 12x16 tile grid
    const int tx = t & 15, ty = t >> 4;
    const int bn = (blk % 12) * 64, bm = (blk / 12) * 64;
    const int am = t >> 2, ak = (t & 3) << 2;
    float acc[4][4] = {};
    for (int k0 = 0; k0 < 768; k0 += 16) {
      float4 av = *(const float4*)(id_tot + (size_t)(bm + am) * 768 + k0 + ak);
      float4 bv = *(const float4*)(W_idv + (size_t)(bn + am) * 768 + k0 + ak);
      As[ak + 0][am] = av.x; As[ak + 1][am] = av.y; As[ak + 2][am] = av.z; As[ak + 3][am] = av.w;
      Bs[ak + 0][am] = bv.x; Bs[ak + 1][am] = bv.y; Bs[ak + 2][am] = bv.z; Bs[ak + 3][am] = bv.w;
      __syncthreads();
#pragma unroll
      for (int kk = 0; kk < 16; ++kk) {
        float4 a4 = *(const float4*)&As[kk][ty << 2];
        float4 b4 = *(const float4*)&Bs[kk][tx << 2];
        float ar[4] = { a4.x, a4.y, a4.z, a4.w };
        float br[4] = { b4.x, b4.y, b4.z, b4.w };
#pragma unroll
        for (int i = 0; i < 4; ++i)
#pragma unroll
          for (int j = 0; j < 4; ++j) acc[i][j] += ar[i] * br[j];
      }
      __syncthreads();
    }
#pragma unroll
    for (int i = 0; i < 4; ++i) {
      int mg = bm + (ty << 2) + i;
#pragma unroll
      for (int j = 0; j < 4; ++j) {
        int col = bn + (tx << 2) + j;
        float v = acc[i][j] + b_idv[col];
        float lo = 0.f;
#pragma unroll
        for (int r = 0; r < 8; ++r) lo += lowv[(size_t)mg * 8 + r] * idv_B[(size_t)col * 8 + r];
        IDV[(size_t)mg * 768 + col] = v + lo * 0.125f;
      }
    }
  } else if (blk < 448) {   // ID_K: 1+tanh (interleaved butterfly reduce)
    int wv = t >> 6, ln = t & 63;
    size_t row = (size_t)(blk - 192) * 4 + wv;
    const float* s = id_tot + row * DIMc;
    float xr[12];
#pragma unroll
    for (int i = 0; i < 12; ++i) xr[i] = s[ln + i * 64];
    float p[12];
#pragma unroll
    for (int h = 0; h < 12; ++h) {
      const float* m = W_idk + (size_t)h * DIMc;
      float acc = 0.f;
#pragma unroll
      for (int i = 0; i < 12; ++i) acc += xr[i] * m[ln + i * 64];
      p[h] = acc;
    }
#pragma unroll
    for (int off = 32; off; off >>= 1)
#pragma unroll
      for (int h = 0; h < 12; ++h) p[h] += __shfl_xor(p[h], off, 64);
    if (ln == 0) {
#pragma unroll
      for (int h = 0; h < 12; ++h) {
        float lo = 0.f;
#pragma unroll
        for (int r = 0; r < 8; ++r) lo += lowk[row * 8 + r] * idk_B[h * 8 + r];
        IDK[row * Hh + h] = 1.f + tanhf(p[h] + b_idk[h] + lo * 0.125f);
      }
    }
  } else {                  // cast_pack A_aug for qkv (2000 blocks)
    int idx = (blk - 448) * 256 + t;      // 5120*100 groups of 8
    int row = idx / 100, c8 = (idx % 100) * 8;
    unsigned int w[4];
    if (c8 < 768) {
      const float* s = x + (size_t)row * 768 + c8;
      float4 a = *(const float4*)s;
      float4 b = *(const float4*)(s + 4);
      w[0] = pk_bf16(a.x, a.y); w[1] = pk_bf16(a.z, a.w);
      w[2] = pk_bf16(b.x, b.y); w[3] = pk_bf16(b.z, b.w);
    } else {
      float v[8];
#pragma unroll
      for (int j = 0; j < 8; ++j) {
        int e = c8 - 768 + j;
        v[j] = (e < 24) ? qlow[(size_t)row * 24 + e] : 0.f;
      }
      w[0] = pk_bf16(v[0], v[1]); w[1] = pk_bf16(v[2], v[3]);
      w[2] = pk_bf16(v[4], v[5]); w[3] = pk_bf16(v[6], v[7]);
    }
    *(uint4*)(Aa + (size_t)row * KAUG + c8) = make_uint4(w[0], w[1], w[2], w[3]);
  }
}

// ---------------- pack A_aug for proj, FUSED with route/plow dots ----------------
__global__ __launch_bounds__(256) void cast_pack_proj(
    const float* __restrict__ xo, const float* __restrict__ routeW,
    const float* __restrict__ projA, unsigned short* __restrict__ dst)
{
  const int wv = threadIdx.x >> 6, ln = threadIdx.x & 63;
  size_t row = (size_t)blockIdx.x * 4 + wv;      // 1280 blocks x 4 rows
  const float* s = xo + row * DIMc;
  float xr[12];
#pragma unroll
  for (int i = 0; i < 12; ++i) xr[i] = s[ln + i * 64];
  float pr[4];
#pragma unroll
  for (int o = 0; o < 4; ++o) {
    const float* m = routeW + (size_t)o * DIMc;
    float acc = 0.f;
#pragma unroll
    for (int i = 0; i < 12; ++i) acc += xr[i] * m[ln + i * 64];
    pr[o] = acc;
  }
  float pl[32];
#pragma unroll
  for (int o = 0; o < 32; ++o) {
    const float* m = projA + (size_t)o * DIMc;
    float acc = 0.f;
#pragma unroll
    for (int i = 0; i < 12; ++i) acc += xr[i] * m[ln + i * 64];
    pl[o] = acc;
  }
#pragma unroll
  for (int off = 32; off; off >>= 1) {
#pragma unroll
    for (int o = 0; o < 4; ++o) pr[o] += __shfl_xor(pr[o], off, 64);
#pragma unroll
    for (int o = 0; o < 32; ++o) pl[o] += __shfl_xor(pl[o], off, 64);
  }
  // softmax over the 4 route logits (all lanes hold identical sums)
  float mx = fmaxf(fmaxf(pr[0], pr[1]), fmaxf(pr[2], pr[3]));
  float e0 = __expf(pr[0] - mx), e1 = __expf(pr[1] - mx),
        e2 = __expf(pr[2] - mx), e3 = __expf(pr[3] - mx);
  float inv = 0.125f / (e0 + e1 + e2 + e3);
  float rt[4] = { e0 * inv, e1 * inv, e2 * inv, e3 * inv };
  // pack the row: 100 groups of 8, lanes stride the groups
  unsigned short* drow = dst + row * KAUG;
  for (int g = ln; g < 100; g += 64) {
    int c8 = g * 8;
    unsigned int w[4];
    if (c8 < 768) {
      const float* p = s + c8;
      float4 a = *(const float4*)p;
      float4 b = *(const float4*)(p + 4);
      w[0] = pk_bf16(a.x, a.y); w[1] = pk_bf16(a.z, a.w);
      w[2] = pk_bf16(b.x, b.y); w[3] = pk_bf16(b.z, b.w);
    } else {
      float v[8];
#pragma unroll
      for (int j = 0; j < 8; ++j) {
        int e = c8 - 768 + j;
        v[j] = (e < 32) ? rt[e >> 3] * pl[e] : 0.f;
      }
      w[0] = pk_bf16(v[0], v[1]); w[1] = pk_bf16(v[2], v[3]);
      w[2] = pk_bf16(v[4], v[5]); w[3] = pk_bf16(v[6], v[7]);
    }
    *(uint4*)(drow + c8) = make_uint4(w[0], w[1], w[2], w[3]);
  }
}

// ---------------- MFMA GEMM: C = A_aug @ W_aug^T + bias, K=800.
//   mode 0 (qkv): fixup (IDK/IDV) fused; v-epilogue transposes IN-LDS and
//   writes vth/vmth bf16 DIRECTLY (transpose_post + vb round-trip removed).
//   Tile facts: 1280 = 10*128 so each 128-row tile is within one batch and
//   tt<256 is tile-uniform (tt0 in {0,128}). Same per-element RNE rounding
//   as the old transpose_post -> bit-identical. ----------------
__global__ __launch_bounds__(256) void gemm_mfma(
    const unsigned short* __restrict__ A, const unsigned short* __restrict__ W,
    const float* __restrict__ bias, int mode, float* __restrict__ dst,
    unsigned short* __restrict__ qh, float* __restrict__ kmid,
    unsigned short* __restrict__ kfh,
    const float* __restrict__ IDK, const float* __restrict__ IDV,
    float* __restrict__ vmid, unsigned short* __restrict__ kmh,
    unsigned short* __restrict__ vth, unsigned short* __restrict__ vmth)
{
  __shared__ unsigned short tlb[128][130];   // v-transpose staging (g==2 only)
  const int t = threadIdx.x, w = t >> 6, l = t & 63;
  const int m = l & 15, quad = l >> 4;
  const int bm = blockIdx.y * 128 + (w >> 1) * 64;
  const int bn = blockIdx.x * 128 + (w & 1) * 64;
  f32x4 acc[4][4] = {};
  const unsigned short* Ab = A + (size_t)(bm + m) * KAUG;
  const unsigned short* Wb = W + (size_t)(bn + m) * KAUG;
  for (int kk = 0; kk < KAUG; kk += 32) {
    bf16x8 af[4], bf[4];
#pragma unroll
    for (int i = 0; i < 4; ++i) af[i] = *(const bf16x8*)(Ab + (size_t)i * 16 * KAUG + kk + quad * 8);
#pragma unroll
    for (int j = 0; j < 4; ++j) bf[j] = *(const bf16x8*)(Wb + (size_t)j * 16 * KAUG + kk + quad * 8);
#pragma unroll
    for (int i = 0; i < 4; ++i)
#pragma unroll
      for (int j = 0; j < 4; ++j)
        acc[i][j] = __builtin_amdgcn_mfma_f32_16x16x32_bf16(af[i], bf[j], acc[i][j], 0, 0, 0);
  }

  float bj[4];
#pragma unroll
  for (int j = 0; j < 4; ++j) bj[j] = bias[bn + j * 16 + m];

  if (mode == 2) {
#pragma unroll
    for (int i = 0; i < 4; ++i)
#pragma unroll
      for (int r = 0; r < 4; ++r) {
        int row = bm + i * 16 + quad * 4 + r;
#pragma unroll
        for (int j = 0; j < 4; ++j)
          dst[(size_t)row * 768 + bn + j * 16 + m] = acc[i][j][r] + bj[j];
      }
    return;
  }
  int g = (blockIdx.x * 128) / DIMc;           // uniform per block
  if (g == 2) {
    // ---- v epilogue: IDV-add (tile-uniform), vmid write, LDS transpose,
    //      direct bf16 write to vth (cols 1280+tt) and vmth (tt<256) ----
    const int tileM = blockIdx.y * 128;
    const int tileN = blockIdx.x * 128;
    const int bb  = tileM / NNtok;
    const int tt0 = tileM % NNtok;
    const int hh0 = (tileN - 2 * DIMc) >> 6;   // head offset of this tile
    const bool idtile = (tt0 < 256);
    const int cl_base = (w & 1) * 64;
    const int rl_base = (w >> 1) * 64;
#pragma unroll
    for (int j = 0; j < 4; ++j) {
      int col_local = cl_base + j * 16 + m;
      int hh = hh0 + (col_local >> 6), d = col_local & 63;
#pragma unroll
      for (int i = 0; i < 4; ++i)
#pragma unroll
        for (int r = 0; r < 4; ++r) {
          int row_local = rl_base + i * 16 + quad * 4 + r;
          float v = acc[i][j][r] + bj[j];
          if (idtile) {
            int tt = tt0 + row_local;
            float vv = v + IDV[(size_t)(bb * 256 + tt) * DIMc + (hh0 << 6) + col_local];
            vmid[((size_t)(bb * Hh + hh) * 256 + tt) * Dd + d] = vv;
            tlb[col_local][row_local] = bf16_1(vv);
          } else {
            tlb[col_local][row_local] = bf16_1(v);
          }
        }
    }
    __syncthreads();
    // write-out: 128 (hh,d) rows x 128 tt, 2 threads per row
    int rloc = t >> 1, half = t & 1;
    int hh = hh0 + (rloc >> 6), d = rloc & 63;
    const unsigned int* src = (const unsigned int*)&tlb[rloc][half * 64];
    unsigned short* dv = vth + (size_t)(bb * Hh + hh) * 163840 + d * 2560 + 1280 + tt0 + half * 64;
#pragma unroll
    for (int q2 = 0; q2 < 8; ++q2)
      *(uint4*)(dv + q2 * 8) = make_uint4(src[q2 * 4 + 0], src[q2 * 4 + 1],
                                          src[q2 * 4 + 2], src[q2 * 4 + 3]);
    if (idtile) {
      unsigned short* dm = vmth + (size_t)(bb * Hh + hh) * 16384 + d * 256 + tt0 + half * 64;
#pragma unroll
      for (int q2 = 0; q2 < 8; ++q2)
        *(uint4*)(dm + q2 * 8) = make_uint4(src[q2 * 4 + 0], src[q2 * 4 + 1],
                                            src[q2 * 4 + 2], src[q2 * 4 + 3]);
    }
    return;
  }
#pragma unroll
  for (int j = 0; j < 4; ++j) {
    int col = bn + j * 16 + m;
    int jj = col - g * DIMc, hh = jj >> 6, d = jj & 63;
#pragma unroll
    for (int i = 0; i < 4; ++i)
#pragma unroll
      for (int r = 0; r < 4; ++r) {
        int row = bm + i * 16 + quad * 4 + r;
        int bb = row / NNtok, tt = row % NNtok;
        float v = acc[i][j][r] + bj[j];
        if (g == 0) {
          qh[((size_t)(bb * Hh + hh) * NNtok + tt) * Dd + d] = bf16_1(v * 0.125f);
        } else {
          kfh[((size_t)(bb * Hh + hh) * 2560 + 1280 + tt) * Dd + d] = bf16_1(v);
          if (tt < 256) {
            float km = v * IDK[(size_t)(bb * 256 + tt) * Hh + hh];
            size_t e = ((size_t)(bb * Hh + hh) * 256 + tt) * Dd + d;
            kmid[e] = km;
            kmh[e] = bf16_1(km);
          }
        }
      }
  }
}

// ---------------- radix helper: select bin from per-wave 256-bin hist ----------------
__device__ __forceinline__ void radix_sel(
    unsigned int* hist, int l, int& kk, int& ceq, unsigned int& bin)
{
  unsigned int h0 = hist[4 * l + 0], h1 = hist[4 * l + 1],
               h2 = hist[4 * l + 2], h3 = hist[4 * l + 3];
  unsigned int s3 = h3, s2 = h2 + s3, s1 = h1 + s2, s0 = h0 + s1;
  unsigned int tsum = s0;
#pragma unroll
  for (int off = 1; off < 64; off <<= 1) {
    unsigned int other = __shfl(tsum, l + off, 64);
    tsum += (l + off < 64) ? other : 0u;
  }
  unsigned int T = tsum - s0;   // suffix over lanes > l
  unsigned int Sv0 = T + s0, Sv1 = T + s1, Sv2 = T + s2, Sv3 = T + s3, Sv4 = T;
  int fb = -1, fkk = 0, fceq = 0;
  unsigned int ukk = (unsigned int)kk;
  if (Sv0 >= ukk && Sv1 < ukk) { fb = 4 * l + 0; fkk = (int)(ukk - Sv1); fceq = (int)(Sv0 - Sv1); }
  if (Sv1 >= ukk && Sv2 < ukk) { fb = 4 * l + 1; fkk = (int)(ukk - Sv2); fceq = (int)(Sv1 - Sv2); }
  if (Sv2 >= ukk && Sv3 < ukk) { fb = 4 * l + 2; fkk = (int)(ukk - Sv3); fceq = (int)(Sv2 - Sv3); }
  if (Sv3 >= ukk && Sv4 < ukk) { fb = 4 * l + 3; fkk = (int)(ukk - Sv4); fceq = (int)(Sv3 - Sv4); }
  unsigned long long mb = __ballot(fb >= 0);
  int src = __ffsll(mb) - 1;
  bin = (unsigned int)__shfl(fb, src, 64);
  kk  = __shfl(fkk, src, 64);
  ceq = __shfl(fceq, src, 64);
}

// ---------------- MFMA top-k attention body (round-4 best-known-good):
//   stage-1 single-pass 256-bin histogram in phase B; sequential per-row
//   finish lambda (no spill); XCD-chunked local-block mapping. ----------------
template<int NK>
__device__ __forceinline__ void attn_body(
    int blk,
    const unsigned short* __restrict__ qh,   // (bh,1280,64) bf16
    const unsigned short* __restrict__ kf,   // (bh,NK,64)   bf16
    const unsigned short* __restrict__ vt,   // (bh,64,NK)   bf16 (V^T)
    int TK, int qrow0, float* __restrict__ xo, int nofs,
    unsigned short* __restrict__ scb, unsigned int* __restrict__ histb,
    float* __restrict__ wavemaxb, float* __restrict__ rowinv)
{
  constexpr int SCP = NK + 8;
  constexpr int W = NK / 128;          // score words per lane per row
  constexpr int NRB = (NK == 256) ? 32 : 128;   // rb blocks per bh

  const int t = threadIdx.x, w = t >> 6, l = t & 63;
  const int xcd  = blk & 7;
  const int slot = blk >> 3;
  const int bh   = xcd * (NBH / 8) + slot / NRB;
  const int rb   = slot % NRB;
  const int b = bh / Hh, h = bh % Hh;
  const int qbase = qrow0 + rb * 8;
  const int m = l & 15, quad = l >> 4;

  // ---- Phase A: QK^T via MFMA (A rows 0-7 = q), 4-deep grouped prefetch ----
  bf16x8 aq0 = {0,0,0,0,0,0,0,0}, aq1 = {0,0,0,0,0,0,0,0};
  if (m < 8) {
    const unsigned short* qp = qh + ((size_t)bh * NNtok + qbase + m) * Dd + quad * 8;
    aq0 = *(const bf16x8*)qp;
    aq1 = *(const bf16x8*)(qp + 32);
  }
  float mx[4] = { -3.0e38f, -3.0e38f, -3.0e38f, -3.0e38f };  // rows quad*4+r
  constexpr int ITA = NK / 64;
  constexpr int GA = (ITA >= 4) ? 4 : ITA;
  const unsigned short* kpA = kf + (size_t)bh * NK * Dd + (size_t)(w * 16 + m) * Dd + quad * 8;
  bf16x8 kbuf[2][GA][2];
#pragma unroll
  for (int i = 0; i < GA; ++i) {
    kbuf[0][i][0] = *(const bf16x8*)(kpA + (size_t)i * 64 * Dd);
    kbuf[0][i][1] = *(const bf16x8*)(kpA + (size_t)i * 64 * Dd + 32);
  }
  int ab = 0;
  for (int g0 = 0; g0 < ITA; g0 += GA) {
    if (g0 + GA < ITA) {
#pragma unroll
      for (int i = 0; i < GA; ++i) {
        kbuf[1 - ab][i][0] = *(const bf16x8*)(kpA + (size_t)(g0 + GA + i) * 64 * Dd);
        kbuf[1 - ab][i][1] = *(const bf16x8*)(kpA + (size_t)(g0 + GA + i) * 64 * Dd + 32);
      }
    }
#pragma unroll
    for (int i = 0; i < GA; ++i) {
      int n0 = w * 16 + (g0 + i) * 64;
      f32x4 acc = {0.f, 0.f, 0.f, 0.f};
      acc = __builtin_amdgcn_mfma_f32_16x16x32_bf16(aq0, kbuf[ab][i][0], acc, 0, 0, 0);
      acc = __builtin_amdgcn_mfma_f32_16x16x32_bf16(aq1, kbuf[ab][i][1], acc, 0, 0, 0);
      if (quad < 2) {    // lanes 0-31 hold rows 0-7 (row = quad*4+reg), col = n0+m
#pragma unroll
        for (int r = 0; r < 4; ++r) {
          float v = acc[r];
          mx[r] = fmaxf(mx[r], v);
          scb[(quad * 4 + r) * SCP + n0 + m] = bf16_1(v);
        }
      }
    }
    ab ^= 1;
  }
#pragma unroll
  for (int off = 1; off < 16; off <<= 1)
#pragma unroll
    for (int r = 0; r < 4; ++r) mx[r] = fmaxf(mx[r], __shfl_xor(mx[r], off, 64));
  if (l == 0) {
#pragma unroll
    for (int r = 0; r < 4; ++r) wavemaxb[w * 8 + r] = mx[r];
  }
  if (l == 16) {
#pragma unroll
    for (int r = 0; r < 4; ++r) wavemaxb[w * 8 + 4 + r] = mx[r];
  }
  __syncthreads();

  // ---- Phase B: load both rows; stage-1 = single-pass 256-bin histogram on
  //      the high byte of the order-transformed bf16 key ----
  const int r0i = w * 2, r1i = w * 2 + 1;
  unsigned int* sp0 = (unsigned int*)(scb + r0i * SCP);
  unsigned int* sp1 = (unsigned int*)(scb + r1i * SCP);
  unsigned int* h0 = histb + r0i * 256;
  unsigned int* h1 = histb + r1i * 256;
#pragma unroll
  for (int z = 0; z < 4; ++z) { h0[l + z * 64] = 0u; h1[l + z * 64] = 0u; }
  unsigned int kw0[W], kw1[W];
#pragma unroll
  for (int j = 0; j < W; ++j) {
    unsigned int v0 = sp0[j * 64 + l];
    unsigned int v1 = sp1[j * 64 + l];
    v0 = v0 ^ (((v0 >> 15) & 0x00010001u) * 0x7fffu + 0x80008000u);
    v1 = v1 ^ (((v1 >> 15) & 0x00010001u) * 0x7fffu + 0x80008000u);
    kw0[j] = v0; kw1[j] = v1;
    atomicAdd(&h0[(v0 >> 8) & 255u], 1u);
    atomicAdd(&h0[v0 >> 24], 1u);
    atomicAdd(&h1[(v1 >> 8) & 255u], 1u);
    atomicAdd(&h1[v1 >> 24], 1u);
  }
  int kk0 = TK, kk1 = TK;
  int ceq0s, ceq1s;
  unsigned int bin0, bin1;
  radix_sel(h0, l, kk0, ceq0s, bin0);
  radix_sel(h1, l, kk1, ceq1s, bin1);
  const unsigned int pf0 = bin0 << 8, pf1 = bin1 << 8;
  (void)ceq0s; (void)ceq1s;

  // ---- stage-2 + ties + exp per row (lambda inlines; kw stays in regs) ----
  auto finish = [&](unsigned int* kwp, unsigned int prefix, int kk, int row,
                    unsigned int* sp) {
    unsigned int* hist = histb + row * 256;
#pragma unroll
    for (int z = 0; z < 4; ++z) hist[l + z * 64] = 0u;
    const unsigned int pfx8 = prefix >> 8;
#pragma unroll
    for (int j = 0; j < W; ++j) {
      unsigned int k2 = kwp[j];
      unsigned int lo = k2 & 0xFFFFu, hi = k2 >> 16;
      if ((lo >> 8) == pfx8) atomicAdd(&hist[lo & 255u], 1u);
      if ((hi >> 8) == pfx8) atomicAdd(&hist[hi & 255u], 1u);
    }
    unsigned int b2;
    int ceq = 0;
    radix_sel(hist, l, kk, ceq, b2);
    const unsigned int Tkey = prefix | b2;
    const int need = kk;
    if (need < ceq) {   // ties at threshold: keep lowest indices (jax order)
      int seen = 0;
      unsigned long long below = (1ull << l) - 1ull;
#pragma unroll
      for (int j = 0; j < W; ++j) {
        unsigned int k2 = kwp[j];
        bool eq0 = ((k2 & 0xFFFFu) == Tkey);
        bool eq1 = ((k2 >> 16) == Tkey);
        unsigned long long m0 = __ballot(eq0), m1 = __ballot(eq1);
        int bfr = __popcll(m0 & below) + __popcll(m1 & below);
        if (eq0 && (seen + bfr) >= need) kwp[j] &= 0xFFFF0000u;
        if (eq1 && (seen + bfr + (eq0 ? 1 : 0)) >= need) kwp[j] &= 0x0000FFFFu;
        seen += __popcll(m0) + __popcll(m1);
      }
    }
    float rm = fmaxf(fmaxf(wavemaxb[0 * 8 + row], wavemaxb[1 * 8 + row]),
                     fmaxf(wavemaxb[2 * 8 + row], wavemaxb[3 * 8 + row]));
    float sum = 0.f;
#pragma unroll
    for (int j = 0; j < W; ++j) {
      unsigned int k2 = kwp[j];
      unsigned int lo = k2 & 0xFFFFu, hi = k2 >> 16;
      unsigned int mm = ((~k2 >> 15) & 0x00010001u) * 0x7fffu + 0x80008000u;
      unsigned int o2 = k2 ^ mm;   // back to bf16 bits
      float v0 = bf2f(o2 & 0xFFFFu);
      float v1 = bf2f(o2 >> 16);
      float w0 = (lo >= Tkey) ? __expf(v0 - rm) : 0.f;
      float w1 = (hi >= Tkey) ? __expf(v1 - rm) : 0.f;
      sp[j * 64 + l] = pk_bf16(w0, w1);
      sum += w0 + w1;
    }
#pragma unroll
    for (int off = 32; off; off >>= 1) sum += __shfl_xor(sum, off, 64);
    if (l == 0) rowinv[row] = 1.f / sum;
  };
  finish(kw0, pf0, kk0, r0i, sp0);
  finish(kw1, pf1, kk1, r1i, sp1);
  __syncthreads();

  // ---- Phase D: PV via MFMA (A rows 0-7 = weights), 4-deep grouped prefetch ----
  constexpr int ITD = NK / 32;
  constexpr int GD = (ITD >= 4) ? 4 : ITD;
  const unsigned short* vrow = vt + (size_t)bh * Dd * NK + (size_t)(w * 16 + m) * NK + quad * 8;
  f32x4 o = {0.f, 0.f, 0.f, 0.f};
  const bf16x8 zz = {0,0,0,0,0,0,0,0};
  bf16x8 vbuf[2][GD], wbuf[2][GD];
#pragma unroll
  for (int i = 0; i < GD; ++i) {
    vbuf[0][i] = *(const bf16x8*)(vrow + i * 32);
    wbuf[0][i] = (m < 8) ? *(const bf16x8*)(scb + m * SCP + i * 32 + quad * 8) : zz;
  }
  int db = 0;
  for (int g0 = 0; g0 < ITD; g0 += GD) {
    if (g0 + GD < ITD) {
#pragma unroll
      for (int i = 0; i < GD; ++i) {
        vbuf[1 - db][i] = *(const bf16x8*)(vrow + (g0 + GD + i) * 32);
        wbuf[1 - db][i] = (m < 8) ? *(const bf16x8*)(scb + m * SCP + (g0 + GD + i) * 32 + quad * 8) : zz;
      }
    }
#pragma unroll
    for (int i = 0; i < GD; ++i)
      o = __builtin_amdgcn_mfma_f32_16x16x32_bf16(wbuf[db][i], vbuf[db][i], o, 0, 0, 0);
    db ^= 1;
  }
  if (quad < 2) {
#pragma unroll
    for (int r = 0; r < 4; ++r) {
      int row = quad * 4 + r;
      int n = nofs + rb * 8 + row;
      xo[((size_t)b * NNtok + n) * DIMc + h * 64 + w * 16 + m] = o[r] * rowinv[row];
    }
  }
}

// ---------------- fused attention launch: blocks [0,6144) = NK=2560,
//   blocks [6144,7680) = NK=256 (backfill the big wave's tail). ----------------
__global__ __launch_bounds__(256, 3) void attn_fused(
    const unsigned short* __restrict__ qh,
    const unsigned short* __restrict__ kfh, const unsigned short* __restrict__ vth,
    const unsigned short* __restrict__ kmh, const unsigned short* __restrict__ vmth,
    float* __restrict__ xo)
{
  __shared__ alignas(16) unsigned short sc_raw[8 * 2568];
  __shared__ unsigned int hist_raw[8 * 256];
  __shared__ float wm_raw[32];
  __shared__ float ri_raw[8];
  if (blockIdx.x < 6144) {
    attn_body<2560>((int)blockIdx.x, qh, kfh, vth, 640, 256, xo, 256,
                    sc_raw, hist_raw, wm_raw, ri_raw);
  } else {
    attn_body<256>((int)blockIdx.x - 6144, qh, kmh, vmth, 128, 0, xo, 0,
                   sc_raw, hist_raw, wm_raw, ri_raw);
  }
}

// ---------------- host ----------------
extern "C" void kernel_launch(void* const* d_in, const int* in_sizes, int n_in,
                              void* d_out, int out_size, void* d_ws, size_t ws_size,
                              hipStream_t stream)
{
  const float* x       = (const float*)d_in[0];
  const float* id_tot  = (const float*)d_in[1];
  const float* mem_k   = (const float*)d_in[2];
  const float* mem_v   = (const float*)d_in[3];
  const float* W_qkv   = (const float*)d_in[4];
  const float* b_qkv   = (const float*)d_in[5];
  const float* qkv_A   = (const float*)d_in[6];
  const float* qkv_B   = (const float*)d_in[7];
  const float* W_proj  = (const float*)d_in[8];
  const float* b_proj  = (const float*)d_in[9];
  const float* route_W = (const float*)d_in[10];
  const float* proj_A  = (const float*)d_in[11];
  const float* proj_B  = (const float*)d_in[12];
  const float* W_idk   = (const float*)d_in[13];
  const float* b_idk   = (const float*)d_in[14];
  const float* idk_A   = (const float*)d_in[15];
  const float* idk_B   = (const float*)d_in[16];
  const float* W_idv   = (const float*)d_in[17];
  const float* b_idv   = (const float*)d_in[18];
  const float* idv_A   = (const float*)d_in[19];
  const float* idv_B   = (const float*)d_in[20];

  float* ws   = (float*)d_ws;
  float* xo   = ws + OXO;
  float* qlow = ws + OQL;
  float* IDK  = ws + OIDK;
  float* IDV  = ws + OIDV;
  float* lowk = ws + OLK;
  float* lowv = ws + OLV;
  unsigned short* qh   = (unsigned short*)(ws + OQH);
  unsigned short* kfh  = (unsigned short*)(ws + OKFH);
  unsigned short* vth  = (unsigned short*)(ws + OVTH);
  unsigned short* kmh  = (unsigned short*)(ws + OKMH);
  unsigned short* vmth = (unsigned short*)(ws + OVMTH);
  unsigned short* Aa   = (unsigned short*)(ws + OAa);
  unsigned short* Wa   = (unsigned short*)(ws + OWa);
  unsigned short* Wa2  = (unsigned short*)(ws + OWa2);

  float* out  = (float*)d_out;
  float* kmid = out + KMID_OFF;
  float* vmid = out + VMID_OFF;

  // staging + LoRA down-dots — one launch
  prep<<<9216, 256, 0, stream>>>(mem_k, mem_v, W_qkv, qkv_B, W_proj, proj_B,
                                 kfh, vth, Wa, Wa2,
                                 x, qkv_A, qlow, id_tot, idk_A, idv_A, lowk, lowv);

  // ID_V GEMM + ID_K tanh + A_aug qkv pack — one launch (all depend only on prep)
  idv_idk_cast<<<2448, 256, 0, stream>>>(id_tot, W_idv, b_idv, lowv, idv_B, IDV,
                                         W_idk, b_idk, lowk, idk_B, IDK,
                                         x, qlow, Aa);

  // QKV via MFMA; fixup fused; v transposed in-LDS -> vth/vmth directly
  gemm_mfma<<<dim3(18, 40), 256, 0, stream>>>(Aa, Wa, b_qkv, 0, nullptr,
                                              qh, kmid, kfh,
                                              IDK, IDV, vmid, kmh, vth, vmth);

  // attention: both dispatches fused (2560-blocks first, 256-blocks fill tail)
  attn_fused<<<7680, 256, 0, stream>>>(qh, kfh, vth, kmh, vmth, xo);

  // routed output projection (route/plow dots fused into the pack)
  cast_pack_proj<<<1280, 256, 0, stream>>>(xo, route_W, proj_A, Aa);
  gemm_mfma<<<dim3(6, 40), 256, 0, stream>>>(Aa, Wa2, b_proj, 2, out,
                                             nullptr, nullptr, nullptr,
                                             nullptr, nullptr, nullptr, nullptr,
                                             nullptr, nullptr);
}

// Round 14
// 804.288 us; speedup vs baseline: 1.1013x; 1.1013x over previous
//
#include <hip/hip_runtime.h>
#include <cstddef>

// ---------------- problem constants ----------------
#define Bq    4
#define Hh    12
#define Dd    64
#define NNtok 1280
#define DIMc  768
#define KAUG  800      // 768 + 32 augmented-K for fused LoRA
#define NBH   48       // Bq*Hh

typedef __attribute__((ext_vector_type(8))) short bf16x8;
typedef __attribute__((ext_vector_type(4))) float f32x4;

// workspace offsets (floats)
static const size_t OVb   = 0;                   // (unused since r11: v goes GEMM->vth directly)
static const size_t OXO   = 3932160;             // xo fp32 (B,1280,768)
static const size_t OQL   = 7864320;             // qkv low (5120,24)
static const size_t OIDK  = 7987200;             // 1+tanh(ID_K) (1024,12)
static const size_t OIDV  = 7999488;             // ID_V (1024,768)
static const size_t OLK   = 8785920;             // id_lowk (1024,8)
static const size_t OLV   = 8794112;             // id_lowv (1024,8)
static const size_t OQH   = 8986624;             // qh bf16 (B,H,1280,64)
static const size_t OKFH  = 10952704;            // kfh bf16 (B,H,2560,64) [mem_k|k]
static const size_t OVTH  = 14884864;            // vth bf16 (B,H,64,2560)
static const size_t OKMH  = 18817024;            // kmh bf16 (B,H,256,64)
static const size_t OVMTH = 19210240;            // vmth bf16 (B,H,64,256)
static const size_t OAa   = 19603456;            // A_aug bf16 (5120,800)
static const size_t OWa   = 21651456;            // W_aug qkv bf16 (2304,800)
static const size_t OWa2  = 22573056;            // W_aug proj bf16 (768,800)

// d_out offsets (floats)
static const size_t KMID_OFF = 3932160;
static const size_t VMID_OFF = 4718592;

__device__ __forceinline__ unsigned int pk_bf16(float a, float b) {  // RNE pack
  unsigned int ua = __float_as_uint(a), ub = __float_as_uint(b);
  ua += 0x7fffu + ((ua >> 16) & 1u);
  ub += 0x7fffu + ((ub >> 16) & 1u);
  return (ua >> 16) | (ub & 0xffff0000u);
}
__device__ __forceinline__ unsigned short bf16_1(float a) {
  unsigned int ua = __float_as_uint(a);
  ua += 0x7fffu + ((ua >> 16) & 1u);
  return (unsigned short)(ua >> 16);
}
__device__ __forceinline__ float bf2f(unsigned int h) {
  return __uint_as_float(h << 16);
}

// ---------------- prep: cast_k | transpose(mem_v) | cast_w_qkv | cast_w_proj
//                  | fused LoRA down-dots (qlow, id lowk/lowv) ----------------
__global__ __launch_bounds__(256) void prep(
    const float* __restrict__ mem_k, const float* __restrict__ mem_v,
    const float* __restrict__ W_qkv, const float* __restrict__ qkvB,
    const float* __restrict__ W_proj, const float* __restrict__ projB,
    unsigned short* __restrict__ kfh, unsigned short* __restrict__ vth,
    unsigned short* __restrict__ Wa, unsigned short* __restrict__ Wa2,
    const float* __restrict__ x, const float* __restrict__ qkvA,
    float* __restrict__ qlow,
    const float* __restrict__ id_tot, const float* __restrict__ idkA,
    const float* __restrict__ idvA, float* __restrict__ lowk,
    float* __restrict__ lowv)
{
  __shared__ float tl[64][65];
  const int blk = blockIdx.x, t = threadIdx.x;
  if (blk < 1920) {                       // cast mem_k -> kfh rows 0..1279
    size_t idx = ((size_t)blk * 256 + t) * 8;
    int bh = (int)(idx / 81920);
    int r  = (int)(idx % 81920);
    const float* s = mem_k + (size_t)bh * 81920 + r;
    float4 a = *(const float4*)s;
    float4 b = *(const float4*)(s + 4);
    unsigned int* dp = (unsigned int*)(kfh + (size_t)bh * 163840 + r);
    dp[0] = pk_bf16(a.x, a.y); dp[1] = pk_bf16(a.z, a.w);
    dp[2] = pk_bf16(b.x, b.y); dp[3] = pk_bf16(b.z, b.w);
  } else if (blk < 2880) {                // transpose mem_v -> vth cols 0..1279
    int b2 = blk - 1920;
    int bh = b2 / 20, t0 = (b2 % 20) * 64;
    const float* sb = mem_v + (size_t)bh * 81920 + (size_t)t0 * 64;
#pragma unroll
    for (int p = 0; p < 4; ++p) {
      int flat = p * 256 + t;
      int r = flat >> 4, c4 = (flat & 15) << 2;
      float4 v = *(const float4*)(sb + r * 64 + c4);
      tl[r][c4 + 0] = v.x; tl[r][c4 + 1] = v.y;
      tl[r][c4 + 2] = v.z; tl[r][c4 + 3] = v.w;
    }
    __syncthreads();
    unsigned short* db = vth + (size_t)bh * 163840 + t0;
#pragma unroll
    for (int p = 0; p < 8; ++p) {
      int flat = p * 256 + t;
      int d = flat >> 5, u = flat & 31;
      *(unsigned int*)(db + (size_t)d * 2560 + 2 * u) = pk_bf16(tl[2 * u][d], tl[2 * u + 1][d]);
    }
  } else if (blk < 6480) {                // W_aug qkv
    int idx = (blk - 2880) * 256 + t;     // 2304*400 uint pairs
    int row = idx / 400, c = (idx % 400) * 2;
    float a, b;
    if (c < 768) {
      a = W_qkv[(size_t)row * 768 + c]; b = W_qkv[(size_t)row * 768 + c + 1];
    } else {
      int g = row / 768, jj = row % 768;
      int e0 = c - 768, e1 = e0 + 1;
      a = (e0 < 24 && (e0 >> 3) == g) ? qkvB[(size_t)g * 6144 + jj * 8 + (e0 & 7)] * 0.125f : 0.f;
      b = (e1 < 24 && (e1 >> 3) == g) ? qkvB[(size_t)g * 6144 + jj * 8 + (e1 & 7)] * 0.125f : 0.f;
    }
    *(unsigned int*)(Wa + (size_t)row * KAUG + c) = pk_bf16(a, b);
  } else if (blk < 7680) {                // W_aug proj
    int idx = (blk - 6480) * 256 + t;     // 768*400
    int row = idx / 400, c = (idx % 400) * 2;
    float a, b;
    if (c < 768) {
      a = W_proj[(size_t)row * 768 + c]; b = W_proj[(size_t)row * 768 + c + 1];
    } else {
      int e0 = c - 768, e1 = e0 + 1;
      a = projB[(size_t)(e0 >> 3) * 6144 + row * 8 + (e0 & 7)];
      b = projB[(size_t)(e1 >> 3) * 6144 + row * 8 + (e1 & 7)];
    }
    *(unsigned int*)(Wa2 + (size_t)row * KAUG + c) = pk_bf16(a, b);
  } else {                                // fused LoRA down-dots
    const int wv = t >> 6, ln = t & 63;
    int b2 = blk - 7680;
    if (b2 < 1280) {                      // qlow: 5120 rows x 24 outputs
      size_t row = (size_t)b2 * 4 + wv;
      const float* s = x + row * DIMc;
      float xr[12];
#pragma unroll
      for (int i = 0; i < 12; ++i) xr[i] = s[ln + i * 64];
      float p[24];
#pragma unroll
      for (int o = 0; o < 24; ++o) {
        const float* m = qkvA + (size_t)o * DIMc;
        float acc = 0.f;
#pragma unroll
        for (int i = 0; i < 12; ++i) acc += xr[i] * m[ln + i * 64];
        p[o] = acc;
      }
#pragma unroll
      for (int off = 32; off; off >>= 1)
#pragma unroll
        for (int o = 0; o < 24; ++o) p[o] += __shfl_xor(p[o], off, 64);
      if (ln == 0) {
#pragma unroll
        for (int o = 0; o < 24; ++o) qlow[row * 24 + o] = p[o];
      }
    } else {                              // id lows: 1024 rows x (8+8)
      size_t row = (size_t)(b2 - 1280) * 4 + wv;
      const float* s = id_tot + row * DIMc;
      float xr[12];
#pragma unroll
      for (int i = 0; i < 12; ++i) xr[i] = s[ln + i * 64];
      float p[16];
#pragma unroll
      for (int o = 0; o < 8; ++o) {
        const float* m1 = idkA + (size_t)o * DIMc;
        const float* m2 = idvA + (size_t)o * DIMc;
        float a1 = 0.f, a2 = 0.f;
#pragma unroll
        for (int i = 0; i < 12; ++i) {
          a1 += xr[i] * m1[ln + i * 64];
          a2 += xr[i] * m2[ln + i * 64];
        }
        p[o] = a1; p[8 + o] = a2;
      }
#pragma unroll
      for (int off = 32; off; off >>= 1)
#pragma unroll
        for (int o = 0; o < 16; ++o) p[o] += __shfl_xor(p[o], off, 64);
      if (ln == 0) {
#pragma unroll
        for (int o = 0; o < 8; ++o) { lowk[row * 8 + o] = p[o]; lowv[row * 8 + o] = p[8 + o]; }
      }
    }
  }
}

// ---------------- merged: idv GEMM (blocks 0..191) | idk tanh (192..447)
//                  | cast_pack A_aug qkv (448..2447) ----------------
__global__ __launch_bounds__(256) void idv_idk_cast(
    const float* __restrict__ id_tot,
    const float* __restrict__ W_idv, const float* __restrict__ b_idv,
    const float* __restrict__ lowv, const float* __restrict__ idv_B,
    float* __restrict__ IDV,
    const float* __restrict__ W_idk, const float* __restrict__ b_idk,
    const float* __restrict__ lowk, const float* __restrict__ idk_B,
    float* __restrict__ IDK,
    const float* __restrict__ x, const float* __restrict__ qlow,
    unsigned short* __restrict__ Aa)
{
  __shared__ alignas(16) float As[16][68];
  __shared__ alignas(16) float Bs[16][68];
  const int blk = blockIdx.x, t = threadIdx.x;
  if (blk < 192) {   // ID_V fp32 GEMM, 12x16 tile grid
    const int tx = t & 15, ty = t >> 4;
    const int bn = (blk % 12) * 64, bm = (blk / 12) * 64;
    const int am = t >> 2, ak = (t & 3) << 2;
    float acc[4][4] = {};
    for (int k0 = 0; k0 < 768; k0 += 16) {
      float4 av = *(const float4*)(id_tot + (size_t)(bm + am) * 768 + k0 + ak);
      float4 bv = *(const float4*)(W_idv + (size_t)(bn + am) * 768 + k0 + ak);
      As[ak + 0][am] = av.x; As[ak + 1][am] = av.y; As[ak + 2][am] = av.z; As[ak + 3][am] = av.w;
      Bs[ak + 0][am] = bv.x; Bs[ak + 1][am] = bv.y; Bs[ak + 2][am] = bv.z; Bs[ak + 3][am] = bv.w;
      __syncthreads();
#pragma unroll
      for (int kk = 0; kk < 16; ++kk) {
        float4 a4 = *(const float4*)&As[kk][ty << 2];
        float4 b4 = *(const float4*)&Bs[kk][tx << 2];
        float ar[4] = { a4.x, a4.y, a4.z, a4.w };
        float br[4] = { b4.x, b4.y, b4.z, b4.w };
#pragma unroll
        for (int i = 0; i < 4; ++i)
#pragma unroll
          for (int j = 0; j < 4; ++j) acc[i][j] += ar[i] * br[j];
      }
      __syncthreads();
    }
#pragma unroll
    for (int i = 0; i < 4; ++i) {
      int mg = bm + (ty << 2) + i;
#pragma unroll
      for (int j = 0; j < 4; ++j) {
        int col = bn + (tx << 2) + j;
        float v = acc[i][j] + b_idv[col];
        float lo = 0.f;
#pragma unroll
        for (int r = 0; r < 8; ++r) lo += lowv[(size_t)mg * 8 + r] * idv_B[(size_t)col * 8 + r];
        IDV[(size_t)mg * 768 + col] = v + lo * 0.125f;
      }
    }
  } else if (blk < 448) {   // ID_K: 1+tanh (interleaved butterfly reduce)
    int wv = t >> 6, ln = t & 63;
    size_t row = (size_t)(blk - 192) * 4 + wv;
    const float* s = id_tot + row * DIMc;
    float xr[12];
#pragma unroll
    for (int i = 0; i < 12; ++i) xr[i] = s[ln + i * 64];
    float p[12];
#pragma unroll
    for (int h = 0; h < 12; ++h) {
      const float* m = W_idk + (size_t)h * DIMc;
      float acc = 0.f;
#pragma unroll
      for (int i = 0; i < 12; ++i) acc += xr[i] * m[ln + i * 64];
      p[h] = acc;
    }
#pragma unroll
    for (int off = 32; off; off >>= 1)
#pragma unroll
      for (int h = 0; h < 12; ++h) p[h] += __shfl_xor(p[h], off, 64);
    if (ln == 0) {
#pragma unroll
      for (int h = 0; h < 12; ++h) {
        float lo = 0.f;
#pragma unroll
        for (int r = 0; r < 8; ++r) lo += lowk[row * 8 + r] * idk_B[h * 8 + r];
        IDK[row * Hh + h] = 1.f + tanhf(p[h] + b_idk[h] + lo * 0.125f);
      }
    }
  } else {                  // cast_pack A_aug for qkv (2000 blocks)
    int idx = (blk - 448) * 256 + t;      // 5120*100 groups of 8
    int row = idx / 100, c8 = (idx % 100) * 8;
    unsigned int w[4];
    if (c8 < 768) {
      const float* s = x + (size_t)row * 768 + c8;
      float4 a = *(const float4*)s;
      float4 b = *(const float4*)(s + 4);
      w[0] = pk_bf16(a.x, a.y); w[1] = pk_bf16(a.z, a.w);
      w[2] = pk_bf16(b.x, b.y); w[3] = pk_bf16(b.z, b.w);
    } else {
      float v[8];
#pragma unroll
      for (int j = 0; j < 8; ++j) {
        int e = c8 - 768 + j;
        v[j] = (e < 24) ? qlow[(size_t)row * 24 + e] : 0.f;
      }
      w[0] = pk_bf16(v[0], v[1]); w[1] = pk_bf16(v[2], v[3]);
      w[2] = pk_bf16(v[4], v[5]); w[3] = pk_bf16(v[6], v[7]);
    }
    *(uint4*)(Aa + (size_t)row * KAUG + c8) = make_uint4(w[0], w[1], w[2], w[3]);
  }
}

// ---------------- pack A_aug for proj, FUSED with route/plow dots ----------------
__global__ __launch_bounds__(256) void cast_pack_proj(
    const float* __restrict__ xo, const float* __restrict__ routeW,
    const float* __restrict__ projA, unsigned short* __restrict__ dst)
{
  const int wv = threadIdx.x >> 6, ln = threadIdx.x & 63;
  size_t row = (size_t)blockIdx.x * 4 + wv;      // 1280 blocks x 4 rows
  const float* s = xo + row * DIMc;
  float xr[12];
#pragma unroll
  for (int i = 0; i < 12; ++i) xr[i] = s[ln + i * 64];
  float pr[4];
#pragma unroll
  for (int o = 0; o < 4; ++o) {
    const float* m = routeW + (size_t)o * DIMc;
    float acc = 0.f;
#pragma unroll
    for (int i = 0; i < 12; ++i) acc += xr[i] * m[ln + i * 64];
    pr[o] = acc;
  }
  float pl[32];
#pragma unroll
  for (int o = 0; o < 32; ++o) {
    const float* m = projA + (size_t)o * DIMc;
    float acc = 0.f;
#pragma unroll
    for (int i = 0; i < 12; ++i) acc += xr[i] * m[ln + i * 64];
    pl[o] = acc;
  }
#pragma unroll
  for (int off = 32; off; off >>= 1) {
#pragma unroll
    for (int o = 0; o < 4; ++o) pr[o] += __shfl_xor(pr[o], off, 64);
#pragma unroll
    for (int o = 0; o < 32; ++o) pl[o] += __shfl_xor(pl[o], off, 64);
  }
  // softmax over the 4 route logits (all lanes hold identical sums)
  float mx = fmaxf(fmaxf(pr[0], pr[1]), fmaxf(pr[2], pr[3]));
  float e0 = __expf(pr[0] - mx), e1 = __expf(pr[1] - mx),
        e2 = __expf(pr[2] - mx), e3 = __expf(pr[3] - mx);
  float inv = 0.125f / (e0 + e1 + e2 + e3);
  float rt[4] = { e0 * inv, e1 * inv, e2 * inv, e3 * inv };
  // pack the row: 100 groups of 8, lanes stride the groups
  unsigned short* drow = dst + row * KAUG;
  for (int g = ln; g < 100; g += 64) {
    int c8 = g * 8;
    unsigned int w[4];
    if (c8 < 768) {
      const float* p = s + c8;
      float4 a = *(const float4*)p;
      float4 b = *(const float4*)(p + 4);
      w[0] = pk_bf16(a.x, a.y); w[1] = pk_bf16(a.z, a.w);
      w[2] = pk_bf16(b.x, b.y); w[3] = pk_bf16(b.z, b.w);
    } else {
      float v[8];
#pragma unroll
      for (int j = 0; j < 8; ++j) {
        int e = c8 - 768 + j;
        v[j] = (e < 32) ? rt[e >> 3] * pl[e] : 0.f;
      }
      w[0] = pk_bf16(v[0], v[1]); w[1] = pk_bf16(v[2], v[3]);
      w[2] = pk_bf16(v[4], v[5]); w[3] = pk_bf16(v[6], v[7]);
    }
    *(uint4*)(drow + c8) = make_uint4(w[0], w[1], w[2], w[3]);
  }
}

// ---------------- MFMA GEMM: C = A_aug @ W_aug^T + bias, K=800.
//   mode 0 (qkv): fixup (IDK/IDV) fused; v-epilogue transposes IN-LDS and
//   writes vth/vmth bf16 DIRECTLY (transpose_post + vb round-trip removed).
//   Tile facts: 1280 = 10*128 so each 128-row tile is within one batch and
//   tt<256 is tile-uniform (tt0 in {0,128}). Same per-element RNE rounding
//   as the old transpose_post -> bit-identical. ----------------
__global__ __launch_bounds__(256) void gemm_mfma(
    const unsigned short* __restrict__ A, const unsigned short* __restrict__ W,
    const float* __restrict__ bias, int mode, float* __restrict__ dst,
    unsigned short* __restrict__ qh, float* __restrict__ kmid,
    unsigned short* __restrict__ kfh,
    const float* __restrict__ IDK, const float* __restrict__ IDV,
    float* __restrict__ vmid, unsigned short* __restrict__ kmh,
    unsigned short* __restrict__ vth, unsigned short* __restrict__ vmth)
{
  __shared__ unsigned short tlb[128][130];   // v-transpose staging (g==2 only)
  const int t = threadIdx.x, w = t >> 6, l = t & 63;
  const int m = l & 15, quad = l >> 4;
  const int bm = blockIdx.y * 128 + (w >> 1) * 64;
  const int bn = blockIdx.x * 128 + (w & 1) * 64;
  f32x4 acc[4][4] = {};
  const unsigned short* Ab = A + (size_t)(bm + m) * KAUG;
  const unsigned short* Wb = W + (size_t)(bn + m) * KAUG;
  for (int kk = 0; kk < KAUG; kk += 32) {
    bf16x8 af[4], bf[4];
#pragma unroll
    for (int i = 0; i < 4; ++i) af[i] = *(const bf16x8*)(Ab + (size_t)i * 16 * KAUG + kk + quad * 8);
#pragma unroll
    for (int j = 0; j < 4; ++j) bf[j] = *(const bf16x8*)(Wb + (size_t)j * 16 * KAUG + kk + quad * 8);
#pragma unroll
    for (int i = 0; i < 4; ++i)
#pragma unroll
      for (int j = 0; j < 4; ++j)
        acc[i][j] = __builtin_amdgcn_mfma_f32_16x16x32_bf16(af[i], bf[j], acc[i][j], 0, 0, 0);
  }

  float bj[4];
#pragma unroll
  for (int j = 0; j < 4; ++j) bj[j] = bias[bn + j * 16 + m];

  if (mode == 2) {
#pragma unroll
    for (int i = 0; i < 4; ++i)
#pragma unroll
      for (int r = 0; r < 4; ++r) {
        int row = bm + i * 16 + quad * 4 + r;
#pragma unroll
        for (int j = 0; j < 4; ++j)
          dst[(size_t)row * 768 + bn + j * 16 + m] = acc[i][j][r] + bj[j];
      }
    return;
  }
  int g = (blockIdx.x * 128) / DIMc;           // uniform per block
  if (g == 2) {
    // ---- v epilogue: IDV-add (tile-uniform), vmid write, LDS transpose,
    //      direct bf16 write to vth (cols 1280+tt) and vmth (tt<256) ----
    const int tileM = blockIdx.y * 128;
    const int tileN = blockIdx.x * 128;
    const int bb  = tileM / NNtok;
    const int tt0 = tileM % NNtok;
    const int hh0 = (tileN - 2 * DIMc) >> 6;   // head offset of this tile
    const bool idtile = (tt0 < 256);
    const int cl_base = (w & 1) * 64;
    const int rl_base = (w >> 1) * 64;
#pragma unroll
    for (int j = 0; j < 4; ++j) {
      int col_local = cl_base + j * 16 + m;
      int hh = hh0 + (col_local >> 6), d = col_local & 63;
#pragma unroll
      for (int i = 0; i < 4; ++i)
#pragma unroll
        for (int r = 0; r < 4; ++r) {
          int row_local = rl_base + i * 16 + quad * 4 + r;
          float v = acc[i][j][r] + bj[j];
          if (idtile) {
            int tt = tt0 + row_local;
            float vv = v + IDV[(size_t)(bb * 256 + tt) * DIMc + (hh0 << 6) + col_local];
            vmid[((size_t)(bb * Hh + hh) * 256 + tt) * Dd + d] = vv;
            tlb[col_local][row_local] = bf16_1(vv);
          } else {
            tlb[col_local][row_local] = bf16_1(v);
          }
        }
    }
    __syncthreads();
    // write-out: 128 (hh,d) rows x 128 tt, 2 threads per row
    int rloc = t >> 1, half = t & 1;
    int hh = hh0 + (rloc >> 6), d = rloc & 63;
    const unsigned int* src = (const unsigned int*)&tlb[rloc][half * 64];
    unsigned short* dv = vth + (size_t)(bb * Hh + hh) * 163840 + d * 2560 + 1280 + tt0 + half * 64;
#pragma unroll
    for (int q2 = 0; q2 < 8; ++q2)
      *(uint4*)(dv + q2 * 8) = make_uint4(src[q2 * 4 + 0], src[q2 * 4 + 1],
                                          src[q2 * 4 + 2], src[q2 * 4 + 3]);
    if (idtile) {
      unsigned short* dm = vmth + (size_t)(bb * Hh + hh) * 16384 + d * 256 + tt0 + half * 64;
#pragma unroll
      for (int q2 = 0; q2 < 8; ++q2)
        *(uint4*)(dm + q2 * 8) = make_uint4(src[q2 * 4 + 0], src[q2 * 4 + 1],
                                            src[q2 * 4 + 2], src[q2 * 4 + 3]);
    }
    return;
  }
#pragma unroll
  for (int j = 0; j < 4; ++j) {
    int col = bn + j * 16 + m;
    int jj = col - g * DIMc, hh = jj >> 6, d = jj & 63;
#pragma unroll
    for (int i = 0; i < 4; ++i)
#pragma unroll
      for (int r = 0; r < 4; ++r) {
        int row = bm + i * 16 + quad * 4 + r;
        int bb = row / NNtok, tt = row % NNtok;
        float v = acc[i][j][r] + bj[j];
        if (g == 0) {
          qh[((size_t)(bb * Hh + hh) * NNtok + tt) * Dd + d] = bf16_1(v * 0.125f);
        } else {
          kfh[((size_t)(bb * Hh + hh) * 2560 + 1280 + tt) * Dd + d] = bf16_1(v);
          if (tt < 256) {
            float km = v * IDK[(size_t)(bb * 256 + tt) * Hh + hh];
            size_t e = ((size_t)(bb * Hh + hh) * 256 + tt) * Dd + d;
            kmid[e] = km;
            kmh[e] = bf16_1(km);
          }
        }
      }
  }
}

// ---------------- radix helper: select bin from per-wave 256-bin hist ----------------
__device__ __forceinline__ void radix_sel(
    unsigned int* hist, int l, int& kk, int& ceq, unsigned int& bin)
{
  unsigned int h0 = hist[4 * l + 0], h1 = hist[4 * l + 1],
               h2 = hist[4 * l + 2], h3 = hist[4 * l + 3];
  unsigned int s3 = h3, s2 = h2 + s3, s1 = h1 + s2, s0 = h0 + s1;
  unsigned int tsum = s0;
#pragma unroll
  for (int off = 1; off < 64; off <<= 1) {
    unsigned int other = __shfl(tsum, l + off, 64);
    tsum += (l + off < 64) ? other : 0u;
  }
  unsigned int T = tsum - s0;   // suffix over lanes > l
  unsigned int Sv0 = T + s0, Sv1 = T + s1, Sv2 = T + s2, Sv3 = T + s3, Sv4 = T;
  int fb = -1, fkk = 0, fceq = 0;
  unsigned int ukk = (unsigned int)kk;
  if (Sv0 >= ukk && Sv1 < ukk) { fb = 4 * l + 0; fkk = (int)(ukk - Sv1); fceq = (int)(Sv0 - Sv1); }
  if (Sv1 >= ukk && Sv2 < ukk) { fb = 4 * l + 1; fkk = (int)(ukk - Sv2); fceq = (int)(Sv1 - Sv2); }
  if (Sv2 >= ukk && Sv3 < ukk) { fb = 4 * l + 2; fkk = (int)(ukk - Sv3); fceq = (int)(Sv2 - Sv3); }
  if (Sv3 >= ukk && Sv4 < ukk) { fb = 4 * l + 3; fkk = (int)(ukk - Sv4); fceq = (int)(Sv3 - Sv4); }
  unsigned long long mb = __ballot(fb >= 0);
  int src = __ffsll(mb) - 1;
  bin = (unsigned int)__shfl(fb, src, 64);
  kk  = __shfl(fkk, src, 64);
  ceq = __shfl(fceq, src, 64);
}

// ---------------- MFMA top-k attention body (round-4 best-known-good):
//   stage-1 single-pass 256-bin histogram in phase B; sequential per-row
//   finish lambda (no spill); XCD-chunked local-block mapping. ----------------
template<int NK>
__device__ __forceinline__ void attn_body(
    int blk,
    const unsigned short* __restrict__ qh,   // (bh,1280,64) bf16
    const unsigned short* __restrict__ kf,   // (bh,NK,64)   bf16
    const unsigned short* __restrict__ vt,   // (bh,64,NK)   bf16 (V^T)
    int TK, int qrow0, float* __restrict__ xo, int nofs,
    unsigned short* __restrict__ scb, unsigned int* __restrict__ histb,
    float* __restrict__ wavemaxb, float* __restrict__ rowinv)
{
  constexpr int SCP = NK + 8;
  constexpr int W = NK / 128;          // score words per lane per row
  constexpr int NRB = (NK == 256) ? 32 : 128;   // rb blocks per bh

  const int t = threadIdx.x, w = t >> 6, l = t & 63;
  const int xcd  = blk & 7;
  const int slot = blk >> 3;
  const int bh   = xcd * (NBH / 8) + slot / NRB;
  const int rb   = slot % NRB;
  const int b = bh / Hh, h = bh % Hh;
  const int qbase = qrow0 + rb * 8;
  const int m = l & 15, quad = l >> 4;

  // ---- Phase A: QK^T via MFMA (A rows 0-7 = q), 4-deep grouped prefetch ----
  bf16x8 aq0 = {0,0,0,0,0,0,0,0}, aq1 = {0,0,0,0,0,0,0,0};
  if (m < 8) {
    const unsigned short* qp = qh + ((size_t)bh * NNtok + qbase + m) * Dd + quad * 8;
    aq0 = *(const bf16x8*)qp;
    aq1 = *(const bf16x8*)(qp + 32);
  }
  float mx[4] = { -3.0e38f, -3.0e38f, -3.0e38f, -3.0e38f };  // rows quad*4+r
  constexpr int ITA = NK / 64;
  constexpr int GA = (ITA >= 4) ? 4 : ITA;
  const unsigned short* kpA = kf + (size_t)bh * NK * Dd + (size_t)(w * 16 + m) * Dd + quad * 8;
  bf16x8 kbuf[2][GA][2];
#pragma unroll
  for (int i = 0; i < GA; ++i) {
    kbuf[0][i][0] = *(const bf16x8*)(kpA + (size_t)i * 64 * Dd);
    kbuf[0][i][1] = *(const bf16x8*)(kpA + (size_t)i * 64 * Dd + 32);
  }
  int ab = 0;
  for (int g0 = 0; g0 < ITA; g0 += GA) {
    if (g0 + GA < ITA) {
#pragma unroll
      for (int i = 0; i < GA; ++i) {
        kbuf[1 - ab][i][0] = *(const bf16x8*)(kpA + (size_t)(g0 + GA + i) * 64 * Dd);
        kbuf[1 - ab][i][1] = *(const bf16x8*)(kpA + (size_t)(g0 + GA + i) * 64 * Dd + 32);
      }
    }
#pragma unroll
    for (int i = 0; i < GA; ++i) {
      int n0 = w * 16 + (g0 + i) * 64;
      f32x4 acc = {0.f, 0.f, 0.f, 0.f};
      acc = __builtin_amdgcn_mfma_f32_16x16x32_bf16(aq0, kbuf[ab][i][0], acc, 0, 0, 0);
      acc = __builtin_amdgcn_mfma_f32_16x16x32_bf16(aq1, kbuf[ab][i][1], acc, 0, 0, 0);
      if (quad < 2) {    // lanes 0-31 hold rows 0-7 (row = quad*4+reg), col = n0+m
#pragma unroll
        for (int r = 0; r < 4; ++r) {
          float v = acc[r];
          mx[r] = fmaxf(mx[r], v);
          scb[(quad * 4 + r) * SCP + n0 + m] = bf16_1(v);
        }
      }
    }
    ab ^= 1;
  }
#pragma unroll
  for (int off = 1; off < 16; off <<= 1)
#pragma unroll
    for (int r = 0; r < 4; ++r) mx[r] = fmaxf(mx[r], __shfl_xor(mx[r], off, 64));
  if (l == 0) {
#pragma unroll
    for (int r = 0; r < 4; ++r) wavemaxb[w * 8 + r] = mx[r];
  }
  if (l == 16) {
#pragma unroll
    for (int r = 0; r < 4; ++r) wavemaxb[w * 8 + 4 + r] = mx[r];
  }
  __syncthreads();

  // ---- Phase B: load both rows; stage-1 = single-pass 256-bin histogram on
  //      the high byte of the order-transformed bf16 key ----
  const int r0i = w * 2, r1i = w * 2 + 1;
  unsigned int* sp0 = (unsigned int*)(scb + r0i * SCP);
  unsigned int* sp1 = (unsigned int*)(scb + r1i * SCP);
  unsigned int* h0 = histb + r0i * 256;
  unsigned int* h1 = histb + r1i * 256;
#pragma unroll
  for (int z = 0; z < 4; ++z) { h0[l + z * 64] = 0u; h1[l + z * 64] = 0u; }
  unsigned int kw0[W], kw1[W];
#pragma unroll
  for (int j = 0; j < W; ++j) {
    unsigned int v0 = sp0[j * 64 + l];
    unsigned int v1 = sp1[j * 64 + l];
    v0 = v0 ^ (((v0 >> 15) & 0x00010001u) * 0x7fffu + 0x80008000u);
    v1 = v1 ^ (((v1 >> 15) & 0x00010001u) * 0x7fffu + 0x80008000u);
    kw0[j] = v0; kw1[j] = v1;
    atomicAdd(&h0[(v0 >> 8) & 255u], 1u);
    atomicAdd(&h0[v0 >> 24], 1u);
    atomicAdd(&h1[(v1 >> 8) & 255u], 1u);
    atomicAdd(&h1[v1 >> 24], 1u);
  }
  int kk0 = TK, kk1 = TK;
  int ceq0s, ceq1s;
  unsigned int bin0, bin1;
  radix_sel(h0, l, kk0, ceq0s, bin0);
  radix_sel(h1, l, kk1, ceq1s, bin1);
  const unsigned int pf0 = bin0 << 8, pf1 = bin1 << 8;
  (void)ceq0s; (void)ceq1s;

  // ---- stage-2 + ties + exp per row (lambda inlines; kw stays in regs) ----
  auto finish = [&](unsigned int* kwp, unsigned int prefix, int kk, int row,
                    unsigned int* sp) {
    unsigned int* hist = histb + row * 256;
#pragma unroll
    for (int z = 0; z < 4; ++z) hist[l + z * 64] = 0u;
    const unsigned int pfx8 = prefix >> 8;
#pragma unroll
    for (int j = 0; j < W; ++j) {
      unsigned int k2 = kwp[j];
      unsigned int lo = k2 & 0xFFFFu, hi = k2 >> 16;
      if ((lo >> 8) == pfx8) atomicAdd(&hist[lo & 255u], 1u);
      if ((hi >> 8) == pfx8) atomicAdd(&hist[hi & 255u], 1u);
    }
    unsigned int b2;
    int ceq = 0;
    radix_sel(hist, l, kk, ceq, b2);
    const unsigned int Tkey = prefix | b2;
    const int need = kk;
    if (need < ceq) {   // ties at threshold: keep lowest indices (jax order)
      int seen = 0;
      unsigned long long below = (1ull << l) - 1ull;
#pragma unroll
      for (int j = 0; j < W; ++j) {
        unsigned int k2 = kwp[j];
        bool eq0 = ((k2 & 0xFFFFu) == Tkey);
        bool eq1 = ((k2 >> 16) == Tkey);
        unsigned long long m0 = __ballot(eq0), m1 = __ballot(eq1);
        int bfr = __popcll(m0 & below) + __popcll(m1 & below);
        if (eq0 && (seen + bfr) >= need) kwp[j] &= 0xFFFF0000u;
        if (eq1 && (seen + bfr + (eq0 ? 1 : 0)) >= need) kwp[j] &= 0x0000FFFFu;
        seen += __popcll(m0) + __popcll(m1);
      }
    }
    float rm = fmaxf(fmaxf(wavemaxb[0 * 8 + row], wavemaxb[1 * 8 + row]),
                     fmaxf(wavemaxb[2 * 8 + row], wavemaxb[3 * 8 + row]));
    float sum = 0.f;
#pragma unroll
    for (int j = 0; j < W; ++j) {
      unsigned int k2 = kwp[j];
      unsigned int lo = k2 & 0xFFFFu, hi = k2 >> 16;
      unsigned int mm = ((~k2 >> 15) & 0x00010001u) * 0x7fffu + 0x80008000u;
      unsigned int o2 = k2 ^ mm;   // back to bf16 bits
      float v0 = bf2f(o2 & 0xFFFFu);
      float v1 = bf2f(o2 >> 16);
      float w0 = (lo >= Tkey) ? __expf(v0 - rm) : 0.f;
      float w1 = (hi >= Tkey) ? __expf(v1 - rm) : 0.f;
      sp[j * 64 + l] = pk_bf16(w0, w1);
      sum += w0 + w1;
    }
#pragma unroll
    for (int off = 32; off; off >>= 1) sum += __shfl_xor(sum, off, 64);
    if (l == 0) rowinv[row] = 1.f / sum;
  };
  finish(kw0, pf0, kk0, r0i, sp0);
  finish(kw1, pf1, kk1, r1i, sp1);
  __syncthreads();

  // ---- Phase D: PV via MFMA (A rows 0-7 = weights), 4-deep grouped prefetch ----
  constexpr int ITD = NK / 32;
  constexpr int GD = (ITD >= 4) ? 4 : ITD;
  const unsigned short* vrow = vt + (size_t)bh * Dd * NK + (size_t)(w * 16 + m) * NK + quad * 8;
  f32x4 o = {0.f, 0.f, 0.f, 0.f};
  const bf16x8 zz = {0,0,0,0,0,0,0,0};
  bf16x8 vbuf[2][GD], wbuf[2][GD];
#pragma unroll
  for (int i = 0; i < GD; ++i) {
    vbuf[0][i] = *(const bf16x8*)(vrow + i * 32);
    wbuf[0][i] = (m < 8) ? *(const bf16x8*)(scb + m * SCP + i * 32 + quad * 8) : zz;
  }
  int db = 0;
  for (int g0 = 0; g0 < ITD; g0 += GD) {
    if (g0 + GD < ITD) {
#pragma unroll
      for (int i = 0; i < GD; ++i) {
        vbuf[1 - db][i] = *(const bf16x8*)(vrow + (g0 + GD + i) * 32);
        wbuf[1 - db][i] = (m < 8) ? *(const bf16x8*)(scb + m * SCP + (g0 + GD + i) * 32 + quad * 8) : zz;
      }
    }
#pragma unroll
    for (int i = 0; i < GD; ++i)
      o = __builtin_amdgcn_mfma_f32_16x16x32_bf16(wbuf[db][i], vbuf[db][i], o, 0, 0, 0);
    db ^= 1;
  }
  if (quad < 2) {
#pragma unroll
    for (int r = 0; r < 4; ++r) {
      int row = quad * 4 + r;
      int n = nofs + rb * 8 + row;
      xo[((size_t)b * NNtok + n) * DIMc + h * 64 + w * 16 + m] = o[r] * rowinv[row];
    }
  }
}

// ---------------- fused attention launch: blocks [0,6144) = NK=2560,
//   blocks [6144,7680) = NK=256 (backfill the big wave's tail). ----------------
__global__ __launch_bounds__(256, 3) void attn_fused(
    const unsigned short* __restrict__ qh,
    const unsigned short* __restrict__ kfh, const unsigned short* __restrict__ vth,
    const unsigned short* __restrict__ kmh, const unsigned short* __restrict__ vmth,
    float* __restrict__ xo)
{
  __shared__ alignas(16) unsigned short sc_raw[8 * 2568];
  __shared__ unsigned int hist_raw[8 * 256];
  __shared__ float wm_raw[32];
  __shared__ float ri_raw[8];
  if (blockIdx.x < 6144) {
    attn_body<2560>((int)blockIdx.x, qh, kfh, vth, 640, 256, xo, 256,
                    sc_raw, hist_raw, wm_raw, ri_raw);
  } else {
    attn_body<256>((int)blockIdx.x - 6144, qh, kmh, vmth, 128, 0, xo, 0,
                   sc_raw, hist_raw, wm_raw, ri_raw);
  }
}

// ---------------- host ----------------
extern "C" void kernel_launch(void* const* d_in, const int* in_sizes, int n_in,
                              void* d_out, int out_size, void* d_ws, size_t ws_size,
                              hipStream_t stream)
{
  const float* x       = (const float*)d_in[0];
  const float* id_tot  = (const float*)d_in[1];
  const float* mem_k   = (const float*)d_in[2];
  const float* mem_v   = (const float*)d_in[3];
  const float* W_qkv   = (const float*)d_in[4];
  const float* b_qkv   = (const float*)d_in[5];
  const float* qkv_A   = (const float*)d_in[6];
  const float* qkv_B   = (const float*)d_in[7];
  const float* W_proj  = (const float*)d_in[8];
  const float* b_proj  = (const float*)d_in[9];
  const float* route_W = (const float*)d_in[10];
  const float* proj_A  = (const float*)d_in[11];
  const float* proj_B  = (const float*)d_in[12];
  const float* W_idk   = (const float*)d_in[13];
  const float* b_idk   = (const float*)d_in[14];
  const float* idk_A   = (const float*)d_in[15];
  const float* idk_B   = (const float*)d_in[16];
  const float* W_idv   = (const float*)d_in[17];
  const float* b_idv   = (const float*)d_in[18];
  const float* idv_A   = (const float*)d_in[19];
  const float* idv_B   = (const float*)d_in[20];

  float* ws   = (float*)d_ws;
  float* xo   = ws + OXO;
  float* qlow = ws + OQL;
  float* IDK  = ws + OIDK;
  float* IDV  = ws + OIDV;
  float* lowk = ws + OLK;
  float* lowv = ws + OLV;
  unsigned short* qh   = (unsigned short*)(ws + OQH);
  unsigned short* kfh  = (unsigned short*)(ws + OKFH);
  unsigned short* vth  = (unsigned short*)(ws + OVTH);
  unsigned short* kmh  = (unsigned short*)(ws + OKMH);
  unsigned short* vmth = (unsigned short*)(ws + OVMTH);
  unsigned short* Aa   = (unsigned short*)(ws + OAa);
  unsigned short* Wa   = (unsigned short*)(ws + OWa);
  unsigned short* Wa2  = (unsigned short*)(ws + OWa2);

  float* out  = (float*)d_out;
  float* kmid = out + KMID_OFF;
  float* vmid = out + VMID_OFF;

  // staging + LoRA down-dots — one launch
  prep<<<9216, 256, 0, stream>>>(mem_k, mem_v, W_qkv, qkv_B, W_proj, proj_B,
                                 kfh, vth, Wa, Wa2,
                                 x, qkv_A, qlow, id_tot, idk_A, idv_A, lowk, lowv);

  // ID_V GEMM + ID_K tanh + A_aug qkv pack — one launch (all depend only on prep)
  idv_idk_cast<<<2448, 256, 0, stream>>>(id_tot, W_idv, b_idv, lowv, idv_B, IDV,
                                         W_idk, b_idk, lowk, idk_B, IDK,
                                         x, qlow, Aa);

  // QKV via MFMA; fixup fused; v transposed in-LDS -> vth/vmth directly
  gemm_mfma<<<dim3(18, 40), 256, 0, stream>>>(Aa, Wa, b_qkv, 0, nullptr,
                                              qh, kmid, kfh,
                                              IDK, IDV, vmid, kmh, vth, vmth);

  // attention: both dispatches fused (2560-blocks first, 256-blocks fill tail)
  attn_fused<<<7680, 256, 0, stream>>>(qh, kfh, vth, kmh, vmth, xo);

  // routed output projection (route/plow dots fused into the pack)
  cast_pack_proj<<<1280, 256, 0, stream>>>(xo, route_W, proj_A, Aa);
  gemm_mfma<<<dim3(6, 40), 256, 0, stream>>>(Aa, Wa2, b_proj, 2, out,
                                             nullptr, nullptr, nullptr,
                                             nullptr, nullptr, nullptr, nullptr,
                                             nullptr, nullptr);
}